// Round 7
// baseline (1321.126 us; speedup 1.0000x reference)
//
#include <hip/hip_runtime.h>
#include <hip/hip_bf16.h>
#include <stdint.h>

#define EDIM 300
#define KP   320      // padded E for MFMA K-loop
#define HDIM 256
#define G4H  1024
#define NB   2048     // both directions' gates
#define TAGS 9
#define BATCH 64
#define SEQ  512
#define MROWS (SEQ*BATCH)   // 32768

typedef _Float16 f16;
typedef _Float16 half2_t __attribute__((ext_vector_type(2)));
typedef _Float16 half8_t __attribute__((ext_vector_type(8)));
typedef float    floatx4 __attribute__((ext_vector_type(4)));
typedef uint32_t u32x4   __attribute__((ext_vector_type(4)));

__device__ __forceinline__ float fast_sigmoid(float x) {
    return __builtin_amdgcn_rcpf(1.f + __expf(-x));
}
__device__ __forceinline__ float fast_tanh(float x) {
    // 1 - 2/(e^{2x}+1); exact at +-inf via rcp(inf)=0
    return 1.f - 2.f*__builtin_amdgcn_rcpf(__expf(2.f*x) + 1.f);
}

// ---- pack input-projection weights [n<1024: wih_f | n>=1024: wih_b], K padded to 320, + fused bias
__global__ void k_pack_wih(const float* __restrict__ wih_f, const float* __restrict__ wih_b,
                           const float* __restrict__ bih_f, const float* __restrict__ bhh_f,
                           const float* __restrict__ bih_b, const float* __restrict__ bhh_b,
                           f16* __restrict__ wpack, float* __restrict__ bias2) {
    int n = blockIdx.x;
    const float* src = (n < G4H) ? (wih_f + (long)n*EDIM) : (wih_b + (long)(n-G4H)*EDIM);
    for (int k = threadIdx.x; k < KP; k += 64)
        wpack[(long)n*KP + k] = (k < EDIM) ? (f16)src[k] : (f16)0.f;
    if (threadIdx.x == 0)
        bias2[n] = (n < G4H) ? (bih_f[n] + bhh_f[n]) : (bih_b[n-G4H] + bhh_b[n-G4H]);
}

// ---- pack recurrent weights into MFMA A-fragment layout for the 8-wave k_recur
// (validated R2/R3): frag index = ((dir*8 + w)*8 + fr)*8 + kf ; 64 lanes x 8 f16.
// A[row][k]: row = lane&15, k = (lane>>4)*8 + j.
// gate row = (fr>>1)*256 + w*32 + (fr&1)*16 + (lane&15); k = kf*32 + (lane>>4)*8 + j.
__global__ void k_pack_whh2(const float* __restrict__ whh_f, const float* __restrict__ whh_b,
                            f16* __restrict__ whhp2) {
    int idx = blockIdx.x*256 + threadIdx.x;   // 65536 = 2*8*8*8*64
    int lane = idx & 63;
    int kf = (idx >> 6) & 7;
    int fr = (idx >> 9) & 7;
    int w  = (idx >> 12) & 7;
    int dir = idx >> 15;
    const float* whh = dir ? whh_b : whh_f;
    int grow = (fr >> 1)*256 + w*32 + (fr & 1)*16 + (lane & 15);
    int k0 = kf*32 + (lane >> 4)*8;
    const float* src = whh + (long)grow*HDIM + k0;
    f16 tmp[8];
    #pragma unroll
    for (int j = 0; j < 8; ++j) tmp[j] = (f16)src[j];
    *(uint4*)(whhp2 + (size_t)idx*8) = *(uint4*)tmp;
}

// ---- embedding gather, f16, row m = t*64+b, padded to KP
__global__ void k_gather(const int* __restrict__ sentence, const float* __restrict__ embed,
                         f16* __restrict__ xg) {
    int m = blockIdx.x;
    int t = m >> 6, b = m & 63;
    int tok = sentence[b*SEQ + t];
    const float* row = embed + (long)tok*EDIM;
    for (int e = threadIdx.x; e < KP; e += 64)
        xg[(long)m*KP + e] = (e < EDIM) ? (f16)row[e] : (f16)0.f;
}

// ---- xp5 GEMM, M=32768 N=2048 K=320; epilogue writes x-preacts so that unit u's
// four gates (i,f,g,o) are adjacent:
// xp5[ ((dir*64 + b)*512 + s)*1024 + u*4 + gate ],  s = dir ? SEQ-1-t : t,
// where col = dir*1024 + gate*256 + u (u = 0..255).  (validated R6)
__launch_bounds__(256)
__global__ void k_gemm_xproj(const f16* __restrict__ xg, const f16* __restrict__ wpack,
                             const float* __restrict__ bias2, f16* __restrict__ xp5) {
    __shared__ __align__(16) f16 As[128*40];
    __shared__ __align__(16) f16 Bs[128*40];
    int tid = threadIdx.x;
    int bm = blockIdx.x, bn = blockIdx.y;
    int wid = tid >> 6, lane = tid & 63;
    int waveM = wid & 1, waveN = wid >> 1;
    int quad = lane >> 4, mlo = lane & 15;
    floatx4 acc[4][4] = {};
    for (int k0 = 0; k0 < KP; k0 += 32) {
        for (int it = 0; it < 2; ++it) {
            int c = tid + it*256;
            int row = c >> 2, ko = (c & 3)*8;
            *(uint4*)(&As[row*40 + ko]) = *(const uint4*)(&xg[(long)(bm*128+row)*KP + k0 + ko]);
            *(uint4*)(&Bs[row*40 + ko]) = *(const uint4*)(&wpack[(long)(bn*128+row)*KP + k0 + ko]);
        }
        __syncthreads();
        half8_t af[4], bf[4];
        #pragma unroll
        for (int i = 0; i < 4; ++i)
            af[i] = *(const half8_t*)(&As[(waveM*64 + i*16 + mlo)*40 + quad*8]);
        #pragma unroll
        for (int j = 0; j < 4; ++j)
            bf[j] = *(const half8_t*)(&Bs[(waveN*64 + j*16 + mlo)*40 + quad*8]);
        #pragma unroll
        for (int i = 0; i < 4; ++i)
            #pragma unroll
            for (int j = 0; j < 4; ++j)
                acc[i][j] = __builtin_amdgcn_mfma_f32_16x16x32_f16(af[i], bf[j], acc[i][j], 0, 0, 0);
        __syncthreads();
    }
    #pragma unroll
    for (int i = 0; i < 4; ++i)
        #pragma unroll
        for (int j = 0; j < 4; ++j) {
            int col = bn*128 + waveN*64 + j*16 + mlo;   // 0..2047
            float bv = bias2[col];
            int dir = col >> 10, grow = col & 1023;
            int gate = grow >> 8, u = grow & 255;
            int rowp = u*4 + gate;
            #pragma unroll
            for (int r = 0; r < 4; ++r) {
                int row = bm*128 + waveM*64 + i*16 + quad*4 + r;
                int t = row >> 6, bb = row & 63;
                int s = dir ? (SEQ-1-t) : t;
                xp5[((size_t)(dir*64 + bb)*512 + s)*1024 + rowp] = (f16)(acc[i][j][r] + bv);
            }
        }
}

// ---- LSTM recurrence on MFMA, one WG per (dir,batch): 128 WGs, 512 threads = 8 waves,
// 2 waves/SIMD for TLP (R6's 1-wave/SIMD exposed all ds_read/cell latency serially).
// Wave w owns gate rows {(fr>>1)*256 + w*32 + (fr&1)*16 + row : fr=0..7} -> 64 frags
// = 8 fr x 8 kf; 64 MFMA/wave/step via inline asm with pinned register classes
// (R6-validated zero-copy): 32 frags AGPR ("a"), 13 VGPR ("v"), 19 LDS (152 KB).
// Per-wave regs ~ 128 A + ~116 V <= 256 (2 waves/SIMD budget) -- no spill, unlike R3.
// Cell: col-0 lanes dump 8 frags to wave-local gbuf; lanes<32 update one unit each.
// One coalesced uint2/lane x-preact from xp5 prefetched a step ahead; one raw
// lgkmcnt(0)+s_barrier per step (global loads stay in flight). h double-buffered.
#define NA 32
#define NV 13
#define NL 19    // 32+13+19 = 64 frags/wave
__launch_bounds__(512, 2)
__global__ void k_recur(const f16* __restrict__ xp5, const f16* __restrict__ whhp2,
                        f16* __restrict__ hcat) {
    __shared__ __align__(16) uint4 ldsW[8*NL*64];      // 152 KB: [w][f-45][lane]
    __shared__ __align__(16) float gbuf[8][8][16];     // 4 KB: [w][fr][q*4+r] (col 0)
    __shared__ __align__(16) f16 hbuf[2][256];         // 1 KB, double buffered
    int dir = blockIdx.x & 1, b = blockIdx.x >> 1;
    int tid = threadIdx.x, w = tid >> 6, lane = tid & 63;
    int q = lane >> 4;

    // ---- stationary W fragments: f 0..31 -> AGPR, 32..44 -> VGPR, 45..63 -> LDS
    const f16* wbase = whhp2 + (size_t)(dir*8 + w)*32768;
    u32x4 wa[NA], wv[NV];
    #pragma unroll
    for (int f = 0; f < NA; ++f)
        wa[f] = *(const u32x4*)(wbase + ((size_t)f*64 + lane)*8);
    #pragma unroll
    for (int f = 0; f < NV; ++f)
        wv[f] = *(const u32x4*)(wbase + ((size_t)(NA + f)*64 + lane)*8);
    #pragma unroll
    for (int f2 = 0; f2 < NL; ++f2)
        ldsW[(w*NL + f2)*64 + lane] =
            *(const uint4*)(wbase + ((size_t)(NA + NV + f2)*64 + lane)*8);

    if (tid < 128) ((uint32_t*)&hbuf[0][0])[tid] = 0u;

    // lanes<32: each owns unit u = w*32 + lane; its 4 gate x-preacts are one uint2
    int u = w*32 + (lane & 31);
    const f16* xs = xp5 + ((size_t)(dir*64 + b)*512)*1024 + u*4;
    uint2 xw = {0u, 0u};
    if ((lane & 63) < 32) xw = *(const uint2*)xs;

    floatx4 zc = {0.f, 0.f, 0.f, 0.f};   // shared zero C-operand
    float cc = 0.f;
    __syncthreads();

    for (int s = 0; s < SEQ; ++s) {
        int t = dir ? (SEQ-1-s) : s;
        // prefetch next step's x (stays in flight across the raw barrier)
        uint2 xn = xw;
        if ((lane & 63) < 32) {
            int sp = (s+1 < SEQ) ? s+1 : s;
            xn = *(const uint2*)(xs + (size_t)sp*1024);
        }
        // ---- 64 MFMA over K=256, constraint-pinned operands (zero-copy W)
        floatx4 acc[8];
        const f16* hp = &hbuf[s & 1][0];
        #pragma unroll
        for (int kf = 0; kf < 8; ++kf) {
            half8_t bf = *(const half8_t*)(hp + kf*32 + q*8);
            #pragma unroll
            for (int fr = 0; fr < 8; ++fr) {
                const int f = fr*8 + kf;
                if (kf == 0) {
                    if (f < NA)
                        asm("v_mfma_f32_16x16x32_f16 %0, %1, %2, %3"
                            : "=&v"(acc[fr]) : "a"(wa[f]), "v"(bf), "v"(zc));
                    else if (f < NA + NV)
                        asm("v_mfma_f32_16x16x32_f16 %0, %1, %2, %3"
                            : "=&v"(acc[fr]) : "v"(wv[f - NA]), "v"(bf), "v"(zc));
                    else {
                        half8_t af = *(const half8_t*)((const f16*)&ldsW[(w*NL + (f - NA - NV))*64 + lane]);
                        asm("v_mfma_f32_16x16x32_f16 %0, %1, %2, %3"
                            : "=&v"(acc[fr]) : "v"(af), "v"(bf), "v"(zc));
                    }
                } else {
                    if (f < NA)
                        asm("v_mfma_f32_16x16x32_f16 %0, %1, %2, %0"
                            : "+v"(acc[fr]) : "a"(wa[f]), "v"(bf));
                    else if (f < NA + NV)
                        asm("v_mfma_f32_16x16x32_f16 %0, %1, %2, %0"
                            : "+v"(acc[fr]) : "v"(wv[f - NA]), "v"(bf));
                    else {
                        half8_t af = *(const half8_t*)((const f16*)&ldsW[(w*NL + (f - NA - NV))*64 + lane]);
                        asm("v_mfma_f32_16x16x32_f16 %0, %1, %2, %0"
                            : "+v"(acc[fr]) : "v"(af), "v"(bf));
                    }
                }
            }
        }
        // ---- col-0 lanes dump gates to wave-local gbuf (in-order DS: no extra sync)
        if ((lane & 15) == 0) {
            #pragma unroll
            for (int fr = 0; fr < 8; ++fr)
                *(floatx4*)&gbuf[w][fr][q*4] = acc[fr];
        }
        // ---- lanes<32 update one unit each: u = w*32 + h16*16 + (lane&15)
        if ((lane & 63) < 32) {
            int h16 = (lane >> 4) & 1, rr = lane & 15;
            half2_t xif = __builtin_bit_cast(half2_t, xw.x);
            half2_t xgo = __builtin_bit_cast(half2_t, xw.y);
            float pi = gbuf[w][0 + h16][rr] + (float)xif[0];
            float pf = gbuf[w][2 + h16][rr] + (float)xif[1];
            float pg = gbuf[w][4 + h16][rr] + (float)xgo[0];
            float po = gbuf[w][6 + h16][rr] + (float)xgo[1];
            float si = fast_sigmoid(pi), sf = fast_sigmoid(pf);
            float tg = fast_tanh(pg),   so = fast_sigmoid(po);
            cc = __builtin_fmaf(sf, cc, si*tg);
            f16 hh = (f16)(so * fast_tanh(cc));
            hbuf[(s+1) & 1][u] = hh;
            hcat[((size_t)t*64 + b)*512 + dir*HDIM + u] = hh;
            xw = xn;
        }
        asm volatile("s_waitcnt lgkmcnt(0)" ::: "memory");
        __builtin_amdgcn_s_barrier();
        asm volatile("" ::: "memory");
    }
}

// ---- emissions: one wave per (t,b) row; lanes split K=512; 9 shuffle-reduced dots
__launch_bounds__(256)
__global__ void k_emis(const f16* __restrict__ hcat, const float* __restrict__ w_out,
                       const float* __restrict__ b_out, float* __restrict__ emis) {
    int r = blockIdx.x*4 + (threadIdx.x >> 6);
    int lane = threadIdx.x & 63;
    float hv[8];
    #pragma unroll
    for (int i = 0; i < 8; ++i) hv[i] = (float)hcat[(long)r*512 + lane + i*64];
    for (int tag = 0; tag < TAGS; ++tag) {
        float acc = 0.f;
        #pragma unroll
        for (int i = 0; i < 8; ++i) acc += hv[i]*w_out[tag*512 + lane + i*64];
        for (int off = 32; off; off >>= 1) acc += __shfl_xor(acc, off);
        if (lane == 0) emis[(long)r*TAGS + tag] = acc + b_out[tag];
    }
}

// ---- CRF: one wave per batch row. Gold score (lane-parallel over t) + forward logZ
__launch_bounds__(256)
__global__ void k_crf(const float* __restrict__ emis, const int* __restrict__ tags,
                      const int* __restrict__ mask, const float* __restrict__ start_trans,
                      const float* __restrict__ end_trans, const float* __restrict__ trans,
                      float* __restrict__ out) {
    int b = blockIdx.x*4 + (threadIdx.x >> 6);
    int lane = threadIdx.x & 63;
    int len = 0;
    #pragma unroll
    for (int i = 0; i < 8; ++i) len += mask[b*SEQ + lane + i*64];
    for (int off = 32; off; off >>= 1) len += __shfl_xor(len, off);
    float sc = 0.f;
    for (int i = 0; i < 8; ++i) {
        int t = 1 + lane + i*64;
        if (t < SEQ && mask[b*SEQ + t]) {
            int tp = tags[b*SEQ + t - 1], tc = tags[b*SEQ + t];
            sc += trans[tp*TAGS + tc] + emis[(long)(t*64 + b)*TAGS + tc];
        }
    }
    for (int off = 32; off; off >>= 1) sc += __shfl_xor(sc, off);
    int tag0 = tags[b*SEQ];
    sc += start_trans[tag0] + emis[(long)b*TAGS + tag0];
    sc += end_trans[tags[b*SEQ + len - 1]];
    bool act = lane < TAGS;
    int j = act ? lane : 0;
    float tcol[TAGS];
    #pragma unroll
    for (int i = 0; i < TAGS; ++i) tcol[i] = trans[i*TAGS + j];
    float alpha = act ? (start_trans[j] + emis[(long)b*TAGS + j]) : -1e30f;
    for (int t = 1; t < SEQ; ++t) {
        int mt = mask[b*SEQ + t];
        float em = emis[(long)(t*64 + b)*TAGS + j];
        float v[TAGS], mx = -1e30f;
        #pragma unroll
        for (int i = 0; i < TAGS; ++i) { v[i] = __shfl(alpha, i) + tcol[i]; mx = fmaxf(mx, v[i]); }
        float ss = 0.f;
        #pragma unroll
        for (int i = 0; i < TAGS; ++i) ss += __expf(v[i] - mx);
        float nxt = mx + __logf(ss) + em;
        if (mt && act) alpha = nxt;
    }
    float fv = act ? (alpha + end_trans[j]) : -1e30f;
    float mx = fv;
    for (int off = 32; off; off >>= 1) mx = fmaxf(mx, __shfl_xor(mx, off));
    float ss = act ? __expf(fv - mx) : 0.f;
    for (int off = 32; off; off >>= 1) ss += __shfl_xor(ss, off);
    float logZ = mx + __logf(ss);
    if (lane == 0) atomicAdd(out, (logZ - sc) * (1.0f/BATCH));
}

extern "C" void kernel_launch(void* const* d_in, const int* in_sizes, int n_in,
                              void* d_out, int out_size, void* d_ws, size_t ws_size,
                              hipStream_t stream) {
    const int*   sentence    = (const int*)  d_in[0];
    const int*   tags        = (const int*)  d_in[1];
    const float* embed       = (const float*)d_in[2];
    const float* wih_f       = (const float*)d_in[3];
    const float* whh_f       = (const float*)d_in[4];
    const float* bih_f       = (const float*)d_in[5];
    const float* bhh_f       = (const float*)d_in[6];
    const float* wih_b       = (const float*)d_in[7];
    const float* whh_b       = (const float*)d_in[8];
    const float* bih_b       = (const float*)d_in[9];
    const float* bhh_b       = (const float*)d_in[10];
    const float* w_out       = (const float*)d_in[11];
    const float* b_out       = (const float*)d_in[12];
    const float* start_trans = (const float*)d_in[13];
    const float* end_trans   = (const float*)d_in[14];
    const float* trans       = (const float*)d_in[15];
    const int*   mask        = (const int*)  d_in[16];

    char* ws = (char*)d_ws;
    f16*   xg     = (f16*)ws;   ws += (size_t)MROWS*KP*2;      // 20.97 MB
    f16*   wpack  = (f16*)ws;   ws += (size_t)NB*KP*2;         // 1.31 MB
    float* bias2  = (float*)ws; ws += (size_t)NB*4;            // 8 KB
    f16*   whhp2  = (f16*)ws;   ws += (size_t)1024*512*2;      // 1.05 MB
    f16*   xp5    = (f16*)ws;   ws += (size_t)MROWS*NB*2;      // 134.2 MB
    f16*   hcat   = (f16*)ws;   ws += (size_t)MROWS*512*2;     // 33.55 MB
    float* emis   = (float*)ws; ws += (size_t)MROWS*TAGS*4;    // 1.18 MB

    hipLaunchKernelGGL(k_pack_wih, dim3(NB), dim3(64), 0, stream,
                       wih_f, wih_b, bih_f, bhh_f, bih_b, bhh_b, wpack, bias2);
    hipLaunchKernelGGL(k_pack_whh2, dim3(256), dim3(256), 0, stream, whh_f, whh_b, whhp2);
    hipLaunchKernelGGL(k_gather, dim3(MROWS), dim3(64), 0, stream, sentence, embed, xg);
    hipLaunchKernelGGL(k_gemm_xproj, dim3(256,16), dim3(256), 0, stream, xg, wpack, bias2, xp5);
    hipLaunchKernelGGL(k_recur, dim3(128), dim3(512), 0, stream, xp5, whhp2, hcat);
    hipLaunchKernelGGL(k_emis, dim3(MROWS/4), dim3(256), 0, stream, hcat, w_out, b_out, emis);
    hipMemsetAsync(d_out, 0, sizeof(float), stream);
    hipLaunchKernelGGL(k_crf, dim3(BATCH/4), dim3(256), 0, stream,
                       emis, tags, mask, start_trans, end_trans, trans, (float*)d_out);
}

// Round 8
// 1285.886 us; speedup vs baseline: 1.0274x; 1.0274x over previous
//
#include <hip/hip_runtime.h>
#include <hip/hip_bf16.h>
#include <stdint.h>

#define EDIM 300
#define KP   320      // padded E for MFMA K-loop
#define HDIM 256
#define G4H  1024
#define NB   2048     // both directions' gates
#define TAGS 9
#define BATCH 64
#define SEQ  512
#define MROWS (SEQ*BATCH)   // 32768

typedef _Float16 f16;
typedef _Float16 half2_t __attribute__((ext_vector_type(2)));
typedef _Float16 half8_t __attribute__((ext_vector_type(8)));
typedef float    floatx4 __attribute__((ext_vector_type(4)));
typedef uint32_t u32x4   __attribute__((ext_vector_type(4)));

__device__ __forceinline__ float fast_sigmoid(float x) {
    return __builtin_amdgcn_rcpf(1.f + __expf(-x));
}
__device__ __forceinline__ float fast_tanh(float x) {
    // 1 - 2/(e^{2x}+1); exact at +-inf via rcp(inf)=0
    return 1.f - 2.f*__builtin_amdgcn_rcpf(__expf(2.f*x) + 1.f);
}

// ---- pack input-projection weights [n<1024: wih_f | n>=1024: wih_b], K padded to 320, + fused bias
__global__ void k_pack_wih(const float* __restrict__ wih_f, const float* __restrict__ wih_b,
                           const float* __restrict__ bih_f, const float* __restrict__ bhh_f,
                           const float* __restrict__ bih_b, const float* __restrict__ bhh_b,
                           f16* __restrict__ wpack, float* __restrict__ bias2) {
    int n = blockIdx.x;
    const float* src = (n < G4H) ? (wih_f + (long)n*EDIM) : (wih_b + (long)(n-G4H)*EDIM);
    for (int k = threadIdx.x; k < KP; k += 64)
        wpack[(long)n*KP + k] = (k < EDIM) ? (f16)src[k] : (f16)0.f;
    if (threadIdx.x == 0)
        bias2[n] = (n < G4H) ? (bih_f[n] + bhh_f[n]) : (bih_b[n-G4H] + bhh_b[n-G4H]);
}

// ---- pack recurrent weights into MFMA A-fragment layout for the 4-wave k_recur.
// Slot order is kf-MAJOR: slot g = kf*16 + fr  (so the LDS-resident frags, g>=90,
// are all consumed in the LAST kf blocks -> their ds_reads hide under the pure-reg
// kf 0..4 MFMA stream).  frag g of (dir,w) at whhp3[((dir*4+w)*128 + g)*512 + lane*8].
// A[row][k]: row = lane&15, k = (lane>>4)*8 + j.
// gate row = (fr>>2)*256 + w*64 + (fr&3)*16 + (lane&15); k = kf*32 + (lane>>4)*8 + j.
__global__ void k_pack_whh3(const float* __restrict__ whh_f, const float* __restrict__ whh_b,
                            f16* __restrict__ whhp3) {
    int idx = blockIdx.x*256 + threadIdx.x;   // 65536 = 2*4*128*64
    int lane = idx & 63;
    int slot = (idx >> 6) & 127;
    int w  = (idx >> 13) & 3;
    int dir = idx >> 15;
    int fr = slot & 15;          // kf-major decomposition
    int kf = slot >> 4;
    const float* whh = dir ? whh_b : whh_f;
    int grow = (fr >> 2)*256 + w*64 + (fr & 3)*16 + (lane & 15);
    int k0 = kf*32 + (lane >> 4)*8;
    const float* src = whh + (long)grow*HDIM + k0;
    f16 tmp[8];
    #pragma unroll
    for (int j = 0; j < 8; ++j) tmp[j] = (f16)src[j];
    *(uint4*)(whhp3 + (size_t)idx*8) = *(uint4*)tmp;
}

// ---- embedding gather, f16, row m = t*64+b, padded to KP
__global__ void k_gather(const int* __restrict__ sentence, const float* __restrict__ embed,
                         f16* __restrict__ xg) {
    int m = blockIdx.x;
    int t = m >> 6, b = m & 63;
    int tok = sentence[b*SEQ + t];
    const float* row = embed + (long)tok*EDIM;
    for (int e = threadIdx.x; e < KP; e += 64)
        xg[(long)m*KP + e] = (e < EDIM) ? (f16)row[e] : (f16)0.f;
}

// ---- xp5 GEMM, M=32768 N=2048 K=320; double-buffered global->reg prefetch so the
// next K-tile's loads fly during MFMA. Epilogue writes x-preacts so unit u's four
// gates (i,f,g,o) are adjacent:
// xp5[ ((dir*64 + b)*512 + s)*1024 + u*4 + gate ],  s = dir ? SEQ-1-t : t,
// where col = dir*1024 + gate*256 + u (u = 0..255).  (validated R6)
__launch_bounds__(256)
__global__ void k_gemm_xproj(const f16* __restrict__ xg, const f16* __restrict__ wpack,
                             const float* __restrict__ bias2, f16* __restrict__ xp5) {
    __shared__ __align__(16) f16 As[128*40];
    __shared__ __align__(16) f16 Bs[128*40];
    int tid = threadIdx.x;
    int bm = blockIdx.x, bn = blockIdx.y;
    int wid = tid >> 6, lane = tid & 63;
    int waveM = wid & 1, waveN = wid >> 1;
    int quad = lane >> 4, mlo = lane & 15;
    // staging coordinates (2 chunks of 256 threads -> 128 rows x 40-padded)
    int c0 = tid,        r0 = c0 >> 2, o0 = (c0 & 3)*8;
    int c1 = tid + 256,  r1 = c1 >> 2, o1 = (c1 & 3)*8;
    const f16* ag = xg    + (long)(bm*128)*KP;
    const f16* bg = wpack + (long)(bn*128)*KP;
    uint4 pa0 = *(const uint4*)(&ag[(long)r0*KP + o0]);
    uint4 pa1 = *(const uint4*)(&ag[(long)r1*KP + o1]);
    uint4 pb0 = *(const uint4*)(&bg[(long)r0*KP + o0]);
    uint4 pb1 = *(const uint4*)(&bg[(long)r1*KP + o1]);
    floatx4 acc[4][4] = {};
    for (int k0 = 0; k0 < KP; k0 += 32) {
        *(uint4*)(&As[r0*40 + o0]) = pa0;
        *(uint4*)(&As[r1*40 + o1]) = pa1;
        *(uint4*)(&Bs[r0*40 + o0]) = pb0;
        *(uint4*)(&Bs[r1*40 + o1]) = pb1;
        __syncthreads();
        if (k0 + 32 < KP) {     // prefetch next K-tile (in flight during MFMA)
            pa0 = *(const uint4*)(&ag[(long)r0*KP + k0+32 + o0]);
            pa1 = *(const uint4*)(&ag[(long)r1*KP + k0+32 + o1]);
            pb0 = *(const uint4*)(&bg[(long)r0*KP + k0+32 + o0]);
            pb1 = *(const uint4*)(&bg[(long)r1*KP + k0+32 + o1]);
        }
        half8_t af[4], bf[4];
        #pragma unroll
        for (int i = 0; i < 4; ++i)
            af[i] = *(const half8_t*)(&As[(waveM*64 + i*16 + mlo)*40 + quad*8]);
        #pragma unroll
        for (int j = 0; j < 4; ++j)
            bf[j] = *(const half8_t*)(&Bs[(waveN*64 + j*16 + mlo)*40 + quad*8]);
        #pragma unroll
        for (int i = 0; i < 4; ++i)
            #pragma unroll
            for (int j = 0; j < 4; ++j)
                acc[i][j] = __builtin_amdgcn_mfma_f32_16x16x32_f16(af[i], bf[j], acc[i][j], 0, 0, 0);
        __syncthreads();
    }
    #pragma unroll
    for (int i = 0; i < 4; ++i)
        #pragma unroll
        for (int j = 0; j < 4; ++j) {
            int col = bn*128 + waveN*64 + j*16 + mlo;   // 0..2047
            float bv = bias2[col];
            int dir = col >> 10, grow = col & 1023;
            int gate = grow >> 8, u = grow & 255;
            int rowp = u*4 + gate;
            #pragma unroll
            for (int r = 0; r < 4; ++r) {
                int row = bm*128 + waveM*64 + i*16 + quad*4 + r;
                int t = row >> 6, bb = row & 63;
                int s = dir ? (SEQ-1-t) : t;
                xp5[((size_t)(dir*64 + bb)*512 + s)*1024 + rowp] = (f16)(acc[i][j][r] + bv);
            }
        }
}

// ---- LSTM recurrence on MFMA, one WG per (dir,batch): 128 WGs, 256 threads = 4 waves,
// 1 wave/SIMD, __launch_bounds__(256,1). Wave w owns gate rows {gate*256+w*64 ..+64}
// for all 4 gates: 16 frags x 8 kf = 128 MFMA/step/wave via inline asm with pinned
// register classes (R6-validated zero-copy). kf-MAJOR frag slots g = kf*16+fr:
// g 0..63 (kf 0..3) in AGPR ("a", full 256), g 64..89 (kf4 + kf5 frs 0..9) in VGPR,
// g 90..127 (kf5 frs 10..15 + kf 6..7) in LDS (38/wave, 152 KB) -- every
// LDS-resident frag is consumed LATE in the step, so its ds_read hides under the
// ~80 pure-register MFMAs; VFRAG 32->26 leaves ~24 spare VGPRs so the scheduler can
// actually hoist those reads. Cell phase: col-0 lanes dump acc to a 4KB wave-local
// gbuf, each of the 64 lanes updates one unit. One coalesced uint2/lane x-preact
// from xp5 prefetched a step ahead; one raw lgkmcnt(0)+s_barrier per step.
#define AFRAG 64
#define VFRAG 26
#define LFRAG 38    // 64+26+38 = 128 frags/wave
__launch_bounds__(256, 1)
__global__ void k_recur(const f16* __restrict__ xp5, const f16* __restrict__ whhp3,
                        f16* __restrict__ hcat) {
    __shared__ __align__(16) uint4 ldsW[4*LFRAG*64];   // 152 KB: [w][g-90][lane]
    __shared__ __align__(16) float gbuf[4][16][16];    // 4 KB: [w][fr][q*4+r] (col 0)
    __shared__ __align__(16) f16 hbuf[2][256];         // 1 KB, double buffered
    int dir = blockIdx.x & 1, b = blockIdx.x >> 1;
    int tid = threadIdx.x, w = tid >> 6, lane = tid & 63;
    int q = lane >> 4;          // k-group / row-quad
    int v = lane;               // unit owned in cell phase: u256 = w*64 + v

    // ---- stationary W fragments: g 0..63 -> AGPR, 64..89 -> VGPR, 90..127 -> LDS
    const f16* wbase = whhp3 + (size_t)(dir*4 + w)*131072;
    u32x4 wa[AFRAG], wv[VFRAG];
    #pragma unroll
    for (int g = 0; g < AFRAG; ++g)
        wa[g] = *(const u32x4*)(wbase + ((size_t)g*64 + lane)*8);
    #pragma unroll
    for (int g = 0; g < VFRAG; ++g)
        wv[g] = *(const u32x4*)(wbase + ((size_t)(AFRAG + g)*64 + lane)*8);
    #pragma unroll
    for (int g2 = 0; g2 < LFRAG; ++g2)
        ldsW[(w*LFRAG + g2)*64 + lane] =
            *(const uint4*)(wbase + ((size_t)(AFRAG + VFRAG + g2)*64 + lane)*8);

    if (tid < 128) ((uint32_t*)&hbuf[0][0])[tid] = 0u;

    // per-lane x source: 4 gate preacts of unit (w*64+v), linear in s
    const f16* xs = xp5 + ((size_t)(dir*64 + b)*512)*1024 + (w*64 + v)*4;
    uint2 xw = *(const uint2*)xs;

    floatx4 zc = {0.f, 0.f, 0.f, 0.f};   // shared zero C-operand, zeroed once
    float cc = 0.f;
    __syncthreads();

    for (int s = 0; s < SEQ; ++s) {
        int t = dir ? (SEQ-1-s) : s;
        // prefetch next step's x (stays in flight across the raw barrier)
        int sp = (s+1 < SEQ) ? s+1 : s;
        uint2 xn = *(const uint2*)(xs + (size_t)sp*1024);
        // ---- 128 MFMA over K=256, kf-major, constraint-pinned operands
        floatx4 acc[16];
        const f16* hp = &hbuf[s & 1][0];
        #pragma unroll
        for (int kf = 0; kf < 8; ++kf) {
            half8_t bf = *(const half8_t*)(hp + kf*32 + q*8);
            #pragma unroll
            for (int fr = 0; fr < 16; ++fr) {
                const int g = kf*16 + fr;
                if (kf == 0) {
                    // g = fr < 16 < AFRAG: always AGPR
                    asm("v_mfma_f32_16x16x32_f16 %0, %1, %2, %3"
                        : "=&v"(acc[fr]) : "a"(wa[g]), "v"(bf), "v"(zc));
                } else {
                    if (g < AFRAG)
                        asm("v_mfma_f32_16x16x32_f16 %0, %1, %2, %0"
                            : "+v"(acc[fr]) : "a"(wa[g]), "v"(bf));
                    else if (g < AFRAG + VFRAG)
                        asm("v_mfma_f32_16x16x32_f16 %0, %1, %2, %0"
                            : "+v"(acc[fr]) : "v"(wv[g - AFRAG]), "v"(bf));
                    else {
                        half8_t af = *(const half8_t*)((const f16*)&ldsW[(w*LFRAG + (g - AFRAG - VFRAG))*64 + lane]);
                        asm("v_mfma_f32_16x16x32_f16 %0, %1, %2, %0"
                            : "+v"(acc[fr]) : "v"(af), "v"(bf));
                    }
                }
            }
        }
        // ---- col-0 lanes dump gates to wave-local gbuf (no cross-wave use -> no barrier)
        if ((lane & 15) == 0) {
            #pragma unroll
            for (int fr = 0; fr < 16; ++fr)
                *(floatx4*)&gbuf[w][fr][q*4] = acc[fr];
        }
        // ---- each lane updates one unit: u256 = w*64 + v
        {
            int sub = v >> 4, rr = v & 15;
            half2_t xif = __builtin_bit_cast(half2_t, xw.x);
            half2_t xgo = __builtin_bit_cast(half2_t, xw.y);
            float pi = gbuf[w][0  + sub][rr] + (float)xif[0];
            float pf = gbuf[w][4  + sub][rr] + (float)xif[1];
            float pg = gbuf[w][8  + sub][rr] + (float)xgo[0];
            float po = gbuf[w][12 + sub][rr] + (float)xgo[1];
            float si = fast_sigmoid(pi), sf = fast_sigmoid(pf);
            float tg = fast_tanh(pg),   so = fast_sigmoid(po);
            cc = __builtin_fmaf(sf, cc, si*tg);
            f16 hh = (f16)(so * fast_tanh(cc));
            hbuf[(s+1) & 1][w*64 + v] = hh;
            hcat[((size_t)t*64 + b)*512 + dir*HDIM + w*64 + v] = hh;
        }
        xw = xn;
        asm volatile("s_waitcnt lgkmcnt(0)" ::: "memory");
        __builtin_amdgcn_s_barrier();
        asm volatile("" ::: "memory");
    }
}

// ---- emissions: one wave per (t,b) row; lanes split K=512; 9 shuffle-reduced dots
__launch_bounds__(256)
__global__ void k_emis(const f16* __restrict__ hcat, const float* __restrict__ w_out,
                       const float* __restrict__ b_out, float* __restrict__ emis) {
    int r = blockIdx.x*4 + (threadIdx.x >> 6);
    int lane = threadIdx.x & 63;
    float hv[8];
    #pragma unroll
    for (int i = 0; i < 8; ++i) hv[i] = (float)hcat[(long)r*512 + lane + i*64];
    for (int tag = 0; tag < TAGS; ++tag) {
        float acc = 0.f;
        #pragma unroll
        for (int i = 0; i < 8; ++i) acc += hv[i]*w_out[tag*512 + lane + i*64];
        for (int off = 32; off; off >>= 1) acc += __shfl_xor(acc, off);
        if (lane == 0) emis[(long)r*TAGS + tag] = acc + b_out[tag];
    }
}

// ---- CRF: one wave per batch row. Gold score (lane-parallel over t) + forward logZ
__launch_bounds__(256)
__global__ void k_crf(const float* __restrict__ emis, const int* __restrict__ tags,
                      const int* __restrict__ mask, const float* __restrict__ start_trans,
                      const float* __restrict__ end_trans, const float* __restrict__ trans,
                      float* __restrict__ out) {
    int b = blockIdx.x*4 + (threadIdx.x >> 6);
    int lane = threadIdx.x & 63;
    int len = 0;
    #pragma unroll
    for (int i = 0; i < 8; ++i) len += mask[b*SEQ + lane + i*64];
    for (int off = 32; off; off >>= 1) len += __shfl_xor(len, off);
    float sc = 0.f;
    for (int i = 0; i < 8; ++i) {
        int t = 1 + lane + i*64;
        if (t < SEQ && mask[b*SEQ + t]) {
            int tp = tags[b*SEQ + t - 1], tc = tags[b*SEQ + t];
            sc += trans[tp*TAGS + tc] + emis[(long)(t*64 + b)*TAGS + tc];
        }
    }
    for (int off = 32; off; off >>= 1) sc += __shfl_xor(sc, off);
    int tag0 = tags[b*SEQ];
    sc += start_trans[tag0] + emis[(long)b*TAGS + tag0];
    sc += end_trans[tags[b*SEQ + len - 1]];
    bool act = lane < TAGS;
    int j = act ? lane : 0;
    float tcol[TAGS];
    #pragma unroll
    for (int i = 0; i < TAGS; ++i) tcol[i] = trans[i*TAGS + j];
    float alpha = act ? (start_trans[j] + emis[(long)b*TAGS + j]) : -1e30f;
    for (int t = 1; t < SEQ; ++t) {
        int mt = mask[b*SEQ + t];
        float em = emis[(long)(t*64 + b)*TAGS + j];
        float v[TAGS], mx = -1e30f;
        #pragma unroll
        for (int i = 0; i < TAGS; ++i) { v[i] = __shfl(alpha, i) + tcol[i]; mx = fmaxf(mx, v[i]); }
        float ss = 0.f;
        #pragma unroll
        for (int i = 0; i < TAGS; ++i) ss += __expf(v[i] - mx);
        float nxt = mx + __logf(ss) + em;
        if (mt && act) alpha = nxt;
    }
    float fv = act ? (alpha + end_trans[j]) : -1e30f;
    float mx = fv;
    for (int off = 32; off; off >>= 1) mx = fmaxf(mx, __shfl_xor(mx, off));
    float ss = act ? __expf(fv - mx) : 0.f;
    for (int off = 32; off; off >>= 1) ss += __shfl_xor(ss, off);
    float logZ = mx + __logf(ss);
    if (lane == 0) atomicAdd(out, (logZ - sc) * (1.0f/BATCH));
}

extern "C" void kernel_launch(void* const* d_in, const int* in_sizes, int n_in,
                              void* d_out, int out_size, void* d_ws, size_t ws_size,
                              hipStream_t stream) {
    const int*   sentence    = (const int*)  d_in[0];
    const int*   tags        = (const int*)  d_in[1];
    const float* embed       = (const float*)d_in[2];
    const float* wih_f       = (const float*)d_in[3];
    const float* whh_f       = (const float*)d_in[4];
    const float* bih_f       = (const float*)d_in[5];
    const float* bhh_f       = (const float*)d_in[6];
    const float* wih_b       = (const float*)d_in[7];
    const float* whh_b       = (const float*)d_in[8];
    const float* bih_b       = (const float*)d_in[9];
    const float* bhh_b       = (const float*)d_in[10];
    const float* w_out       = (const float*)d_in[11];
    const float* b_out       = (const float*)d_in[12];
    const float* start_trans = (const float*)d_in[13];
    const float* end_trans   = (const float*)d_in[14];
    const float* trans       = (const float*)d_in[15];
    const int*   mask        = (const int*)  d_in[16];

    char* ws = (char*)d_ws;
    f16*   xg     = (f16*)ws;   ws += (size_t)MROWS*KP*2;      // 20.97 MB
    f16*   wpack  = (f16*)ws;   ws += (size_t)NB*KP*2;         // 1.31 MB
    float* bias2  = (float*)ws; ws += (size_t)NB*4;            // 8 KB
    f16*   whhp3  = (f16*)ws;   ws += (size_t)1024*512*2;      // 1.05 MB
    f16*   xp5    = (f16*)ws;   ws += (size_t)MROWS*NB*2;      // 134.2 MB
    f16*   hcat   = (f16*)ws;   ws += (size_t)MROWS*512*2;     // 33.55 MB
    float* emis   = (float*)ws; ws += (size_t)MROWS*TAGS*4;    // 1.18 MB

    hipLaunchKernelGGL(k_pack_wih, dim3(NB), dim3(64), 0, stream,
                       wih_f, wih_b, bih_f, bhh_f, bih_b, bhh_b, wpack, bias2);
    hipLaunchKernelGGL(k_pack_whh3, dim3(256), dim3(256), 0, stream, whh_f, whh_b, whhp3);
    hipLaunchKernelGGL(k_gather, dim3(MROWS), dim3(64), 0, stream, sentence, embed, xg);
    hipLaunchKernelGGL(k_gemm_xproj, dim3(256,16), dim3(256), 0, stream, xg, wpack, bias2, xp5);
    hipLaunchKernelGGL(k_recur, dim3(128), dim3(256), 0, stream, xp5, whhp3, hcat);
    hipLaunchKernelGGL(k_emis, dim3(MROWS/4), dim3(256), 0, stream, hcat, w_out, b_out, emis);
    hipMemsetAsync(d_out, 0, sizeof(float), stream);
    hipLaunchKernelGGL(k_crf, dim3(BATCH/4), dim3(256), 0, stream,
                       emis, tags, mask, start_trans, end_trans, trans, (float*)d_out);
}

// Round 9
// 1237.454 us; speedup vs baseline: 1.0676x; 1.0391x over previous
//
#include <hip/hip_runtime.h>
#include <hip/hip_bf16.h>
#include <hip/hip_fp8.h>
#include <stdint.h>

#define EDIM 300
#define KP   320      // padded E for MFMA K-loop
#define HDIM 256
#define G4H  1024
#define NB   2048     // both directions' gates
#define TAGS 9
#define BATCH 64
#define SEQ  512
#define MROWS (SEQ*BATCH)   // 32768

typedef _Float16 f16;
typedef _Float16 half2_t __attribute__((ext_vector_type(2)));
typedef _Float16 half8_t __attribute__((ext_vector_type(8)));
typedef float    floatx4 __attribute__((ext_vector_type(4)));
typedef uint32_t u32x2   __attribute__((ext_vector_type(2)));

__device__ __forceinline__ float fast_sigmoid(float x) {
    return __builtin_amdgcn_rcpf(1.f + __expf(-x));
}
__device__ __forceinline__ float fast_tanh(float x) {
    // 1 - 2/(e^{2x}+1); exact at +-inf via rcp(inf)=0
    return 1.f - 2.f*__builtin_amdgcn_rcpf(__expf(2.f*x) + 1.f);
}
__device__ __forceinline__ uint8_t to_e4m3(float x) {
    __hip_fp8_e4m3 q(x);
    return __builtin_bit_cast(uint8_t, q);
}

// ---- pack input-projection weights [n<1024: wih_f | n>=1024: wih_b], K padded to 320, + fused bias
__global__ void k_pack_wih(const float* __restrict__ wih_f, const float* __restrict__ wih_b,
                           const float* __restrict__ bih_f, const float* __restrict__ bhh_f,
                           const float* __restrict__ bih_b, const float* __restrict__ bhh_b,
                           f16* __restrict__ wpack, float* __restrict__ bias2) {
    int n = blockIdx.x;
    const float* src = (n < G4H) ? (wih_f + (long)n*EDIM) : (wih_b + (long)(n-G4H)*EDIM);
    for (int k = threadIdx.x; k < KP; k += 64)
        wpack[(long)n*KP + k] = (k < EDIM) ? (f16)src[k] : (f16)0.f;
    if (threadIdx.x == 0)
        bias2[n] = (n < G4H) ? (bih_f[n] + bhh_f[n]) : (bih_b[n-G4H] + bhh_b[n-G4H]);
}

// ---- pack recurrent weights into fp8-e4m3 MFMA A-fragment layout, SCALED x16
// (e4m3 min normal 2^-6; weights ~U(-1/16,1/16) -> x16 keeps 98.5% in normals).
// frag g = fr*8 + kf of (dir,w) chunk at whhp8[((dir*4+w)*128 + g)*512 + lane*8].
// A[row][k] (16x16x32 fp8, 2 regs = 8 fp8/lane): row = lane&15, k = (lane>>4)*8 + j.
// gate row = (fr>>2)*256 + w*64 + (fr&3)*16 + (lane&15); k = kf*32 + (lane>>4)*8 + j.
// (geometry identical to the R5/R6-validated f16 whhp3 mapping)
__global__ void k_pack_whh8(const float* __restrict__ whh_f, const float* __restrict__ whh_b,
                            uint8_t* __restrict__ whhp8) {
    int idx = blockIdx.x*256 + threadIdx.x;   // 65536 = 2*4*16*8*64
    int lane = idx & 63;
    int kf = (idx >> 6) & 7;
    int fr = (idx >> 9) & 15;
    int w  = (idx >> 13) & 3;
    int dir = idx >> 15;
    const float* whh = dir ? whh_b : whh_f;
    int grow = (fr >> 2)*256 + w*64 + (fr & 3)*16 + (lane & 15);
    int k0 = kf*32 + (lane >> 4)*8;
    const float* src = whh + (long)grow*HDIM + k0;
    uint8_t tmp[8];
    #pragma unroll
    for (int j = 0; j < 8; ++j) tmp[j] = to_e4m3(src[j] * 16.f);
    *(uint2*)(whhp8 + (size_t)idx*8) = *(uint2*)tmp;
}

// ---- embedding gather, f16, row m = t*64+b, padded to KP
__global__ void k_gather(const int* __restrict__ sentence, const float* __restrict__ embed,
                         f16* __restrict__ xg) {
    int m = blockIdx.x;
    int t = m >> 6, b = m & 63;
    int tok = sentence[b*SEQ + t];
    const float* row = embed + (long)tok*EDIM;
    for (int e = threadIdx.x; e < KP; e += 64)
        xg[(long)m*KP + e] = (e < EDIM) ? (f16)row[e] : (f16)0.f;
}

// ---- xp5 GEMM, M=32768 N=2048 K=320; double-buffered global->reg prefetch.
// Epilogue writes x-preacts so unit u's four gates (i,f,g,o) are adjacent:
// xp5[ ((dir*64 + b)*512 + s)*1024 + u*4 + gate ],  s = dir ? SEQ-1-t : t,
// where col = dir*1024 + gate*256 + u.  (validated R6)
__launch_bounds__(256)
__global__ void k_gemm_xproj(const f16* __restrict__ xg, const f16* __restrict__ wpack,
                             const float* __restrict__ bias2, f16* __restrict__ xp5) {
    __shared__ __align__(16) f16 As[128*40];
    __shared__ __align__(16) f16 Bs[128*40];
    int tid = threadIdx.x;
    int bm = blockIdx.x, bn = blockIdx.y;
    int wid = tid >> 6, lane = tid & 63;
    int waveM = wid & 1, waveN = wid >> 1;
    int quad = lane >> 4, mlo = lane & 15;
    int c0 = tid,        r0 = c0 >> 2, o0 = (c0 & 3)*8;
    int c1 = tid + 256,  r1 = c1 >> 2, o1 = (c1 & 3)*8;
    const f16* ag = xg    + (long)(bm*128)*KP;
    const f16* bg = wpack + (long)(bn*128)*KP;
    uint4 pa0 = *(const uint4*)(&ag[(long)r0*KP + o0]);
    uint4 pa1 = *(const uint4*)(&ag[(long)r1*KP + o1]);
    uint4 pb0 = *(const uint4*)(&bg[(long)r0*KP + o0]);
    uint4 pb1 = *(const uint4*)(&bg[(long)r1*KP + o1]);
    floatx4 acc[4][4] = {};
    for (int k0 = 0; k0 < KP; k0 += 32) {
        *(uint4*)(&As[r0*40 + o0]) = pa0;
        *(uint4*)(&As[r1*40 + o1]) = pa1;
        *(uint4*)(&Bs[r0*40 + o0]) = pb0;
        *(uint4*)(&Bs[r1*40 + o1]) = pb1;
        __syncthreads();
        if (k0 + 32 < KP) {     // prefetch next K-tile (in flight during MFMA)
            pa0 = *(const uint4*)(&ag[(long)r0*KP + k0+32 + o0]);
            pa1 = *(const uint4*)(&ag[(long)r1*KP + k0+32 + o1]);
            pb0 = *(const uint4*)(&bg[(long)r0*KP + k0+32 + o0]);
            pb1 = *(const uint4*)(&bg[(long)r1*KP + k0+32 + o1]);
        }
        half8_t af[4], bf[4];
        #pragma unroll
        for (int i = 0; i < 4; ++i)
            af[i] = *(const half8_t*)(&As[(waveM*64 + i*16 + mlo)*40 + quad*8]);
        #pragma unroll
        for (int j = 0; j < 4; ++j)
            bf[j] = *(const half8_t*)(&Bs[(waveN*64 + j*16 + mlo)*40 + quad*8]);
        #pragma unroll
        for (int i = 0; i < 4; ++i)
            #pragma unroll
            for (int j = 0; j < 4; ++j)
                acc[i][j] = __builtin_amdgcn_mfma_f32_16x16x32_f16(af[i], bf[j], acc[i][j], 0, 0, 0);
        __syncthreads();
    }
    #pragma unroll
    for (int i = 0; i < 4; ++i)
        #pragma unroll
        for (int j = 0; j < 4; ++j) {
            int col = bn*128 + waveN*64 + j*16 + mlo;   // 0..2047
            float bv = bias2[col];
            int dir = col >> 10, grow = col & 1023;
            int gate = grow >> 8, u = grow & 255;
            int rowp = u*4 + gate;
            #pragma unroll
            for (int r = 0; r < 4; ++r) {
                int row = bm*128 + waveM*64 + i*16 + quad*4 + r;
                int t = row >> 6, bb = row & 63;
                int s = dir ? (SEQ-1-t) : t;
                xp5[((size_t)(dir*64 + bb)*512 + s)*1024 + rowp] = (f16)(acc[i][j][r] + bv);
            }
        }
}

// ---- LSTM recurrence on fp8 MFMA, one WG per (dir,batch): 128 WGs, 256 threads =
// 4 waves, 1 wave/SIMD. Wave w owns gate rows {gate*256+w*64 ..+64} for all 4 gates:
// 16 fr x 8 kf = 128 MFMA/step/wave (v_mfma_f32_16x16x32_fp8_fp8; same geometry as
// the R5/R6-validated f16 version). fp8 W = 256 KB/CU -> ALL 128 frags/wave live in
// exactly 256 AGPRs ("a" asm operands, zero-copy, zero per-step W loads); VGPRs
// (~120) hold acc/temps with real scheduling slack. W scaled x16, h stored x16 in
// e4m3 (keeps both in e4m3 normal range); cell un-scales with one fma (1/256).
// Cell: col-0 lanes dump acc to wave-local gbuf; each of 64 lanes updates one unit.
// One coalesced uint2/lane x-preact from xp5 prefetched a step ahead; one raw
// lgkmcnt(0)+s_barrier per step. h double-buffered in LDS as 256 fp8 bytes.
__launch_bounds__(256, 1)
__global__ void k_recur(const f16* __restrict__ xp5, const uint8_t* __restrict__ whhp8,
                        f16* __restrict__ hcat) {
    __shared__ __align__(16) float gbuf[4][16][16];    // 4 KB: [w][fr][q*4+r] (col 0)
    __shared__ __align__(8) uint8_t hbuf[2][256];      // 512 B, x16-scaled e4m3 h
    int dir = blockIdx.x & 1, b = blockIdx.x >> 1;
    int tid = threadIdx.x, w = tid >> 6, lane = tid & 63;
    int q = lane >> 4;          // k-group / row-quad
    int v = lane;               // unit owned in cell phase: u256 = w*64 + v

    // ---- all 128 W fragments -> AGPR (2 regs each = 256 AGPRs exactly)
    const uint8_t* wbase = whhp8 + (size_t)(dir*4 + w)*65536;
    u32x2 wa[128];
    #pragma unroll
    for (int g = 0; g < 128; ++g)
        wa[g] = *(const u32x2*)(wbase + ((size_t)g*64 + lane)*8);

    if (tid < 64) ((uint32_t*)&hbuf[0][0])[tid] = 0u;

    // per-lane x source: 4 gate preacts of unit (w*64+v), linear in s
    const f16* xs = xp5 + ((size_t)(dir*64 + b)*512)*1024 + (w*64 + v)*4;
    uint2 xw = *(const uint2*)xs;

    floatx4 zc = {0.f, 0.f, 0.f, 0.f};   // shared zero C-operand
    float cc = 0.f;
    __syncthreads();

    for (int s = 0; s < SEQ; ++s) {
        int t = dir ? (SEQ-1-s) : s;
        // prefetch next step's x (stays in flight across the raw barrier)
        int sp = (s+1 < SEQ) ? s+1 : s;
        uint2 xn = *(const uint2*)(xs + (size_t)sp*1024);
        // ---- 128 fp8 MFMA over K=256, A pinned in AGPR (zero-copy)
        floatx4 acc[16];
        const uint8_t* hp = &hbuf[s & 1][0];
        #pragma unroll
        for (int kf = 0; kf < 8; ++kf) {
            u32x2 bf2 = *(const u32x2*)(hp + kf*32 + q*8);
            #pragma unroll
            for (int fr = 0; fr < 16; ++fr) {
                const int g = fr*8 + kf;
                if (kf == 0)
                    asm("v_mfma_f32_16x16x32_fp8_fp8 %0, %1, %2, %3"
                        : "=&v"(acc[fr]) : "a"(wa[g]), "v"(bf2), "v"(zc));
                else
                    asm("v_mfma_f32_16x16x32_fp8_fp8 %0, %1, %2, %0"
                        : "+v"(acc[fr]) : "a"(wa[g]), "v"(bf2));
            }
        }
        // ---- col-0 lanes dump gates to wave-local gbuf (no cross-wave use -> no barrier)
        if ((lane & 15) == 0) {
            #pragma unroll
            for (int fr = 0; fr < 16; ++fr)
                *(floatx4*)&gbuf[w][fr][q*4] = acc[fr];
        }
        // ---- each lane updates one unit: u256 = w*64 + v ; un-scale by 1/256
        {
            const float is = 1.f/256.f;
            int sub = v >> 4, rr = v & 15;
            half2_t xif = __builtin_bit_cast(half2_t, xw.x);
            half2_t xgo = __builtin_bit_cast(half2_t, xw.y);
            float pi = __builtin_fmaf(gbuf[w][0  + sub][rr], is, (float)xif[0]);
            float pf = __builtin_fmaf(gbuf[w][4  + sub][rr], is, (float)xif[1]);
            float pg = __builtin_fmaf(gbuf[w][8  + sub][rr], is, (float)xgo[0]);
            float po = __builtin_fmaf(gbuf[w][12 + sub][rr], is, (float)xgo[1]);
            float si = fast_sigmoid(pi), sf = fast_sigmoid(pf);
            float tg = fast_tanh(pg),   so = fast_sigmoid(po);
            cc = __builtin_fmaf(sf, cc, si*tg);
            float hh = so * fast_tanh(cc);
            hbuf[(s+1) & 1][w*64 + v] = to_e4m3(hh * 16.f);
            hcat[((size_t)t*64 + b)*512 + dir*HDIM + w*64 + v] = (f16)hh;
        }
        xw = xn;
        asm volatile("s_waitcnt lgkmcnt(0)" ::: "memory");
        __builtin_amdgcn_s_barrier();
        asm volatile("" ::: "memory");
    }
}

// ---- emissions: one wave per (t,b) row; lanes split K=512; 9 shuffle-reduced dots
__launch_bounds__(256)
__global__ void k_emis(const f16* __restrict__ hcat, const float* __restrict__ w_out,
                       const float* __restrict__ b_out, float* __restrict__ emis) {
    int r = blockIdx.x*4 + (threadIdx.x >> 6);
    int lane = threadIdx.x & 63;
    float hv[8];
    #pragma unroll
    for (int i = 0; i < 8; ++i) hv[i] = (float)hcat[(long)r*512 + lane + i*64];
    for (int tag = 0; tag < TAGS; ++tag) {
        float acc = 0.f;
        #pragma unroll
        for (int i = 0; i < 8; ++i) acc += hv[i]*w_out[tag*512 + lane + i*64];
        for (int off = 32; off; off >>= 1) acc += __shfl_xor(acc, off);
        if (lane == 0) emis[(long)r*TAGS + tag] = acc + b_out[tag];
    }
}

// ---- CRF: one wave per batch row. Gold score (lane-parallel over t) + forward logZ
__launch_bounds__(256)
__global__ void k_crf(const float* __restrict__ emis, const int* __restrict__ tags,
                      const int* __restrict__ mask, const float* __restrict__ start_trans,
                      const float* __restrict__ end_trans, const float* __restrict__ trans,
                      float* __restrict__ out) {
    int b = blockIdx.x*4 + (threadIdx.x >> 6);
    int lane = threadIdx.x & 63;
    int len = 0;
    #pragma unroll
    for (int i = 0; i < 8; ++i) len += mask[b*SEQ + lane + i*64];
    for (int off = 32; off; off >>= 1) len += __shfl_xor(len, off);
    float sc = 0.f;
    for (int i = 0; i < 8; ++i) {
        int t = 1 + lane + i*64;
        if (t < SEQ && mask[b*SEQ + t]) {
            int tp = tags[b*SEQ + t - 1], tc = tags[b*SEQ + t];
            sc += trans[tp*TAGS + tc] + emis[(long)(t*64 + b)*TAGS + tc];
        }
    }
    for (int off = 32; off; off >>= 1) sc += __shfl_xor(sc, off);
    int tag0 = tags[b*SEQ];
    sc += start_trans[tag0] + emis[(long)b*TAGS + tag0];
    sc += end_trans[tags[b*SEQ + len - 1]];
    bool act = lane < TAGS;
    int j = act ? lane : 0;
    float tcol[TAGS];
    #pragma unroll
    for (int i = 0; i < TAGS; ++i) tcol[i] = trans[i*TAGS + j];
    float alpha = act ? (start_trans[j] + emis[(long)b*TAGS + j]) : -1e30f;
    for (int t = 1; t < SEQ; ++t) {
        int mt = mask[b*SEQ + t];
        float em = emis[(long)(t*64 + b)*TAGS + j];
        float v[TAGS], mx = -1e30f;
        #pragma unroll
        for (int i = 0; i < TAGS; ++i) { v[i] = __shfl(alpha, i) + tcol[i]; mx = fmaxf(mx, v[i]); }
        float ss = 0.f;
        #pragma unroll
        for (int i = 0; i < TAGS; ++i) ss += __expf(v[i] - mx);
        float nxt = mx + __logf(ss) + em;
        if (mt && act) alpha = nxt;
    }
    float fv = act ? (alpha + end_trans[j]) : -1e30f;
    float mx = fv;
    for (int off = 32; off; off >>= 1) mx = fmaxf(mx, __shfl_xor(mx, off));
    float ss = act ? __expf(fv - mx) : 0.f;
    for (int off = 32; off; off >>= 1) ss += __shfl_xor(ss, off);
    float logZ = mx + __logf(ss);
    if (lane == 0) atomicAdd(out, (logZ - sc) * (1.0f/BATCH));
}

extern "C" void kernel_launch(void* const* d_in, const int* in_sizes, int n_in,
                              void* d_out, int out_size, void* d_ws, size_t ws_size,
                              hipStream_t stream) {
    const int*   sentence    = (const int*)  d_in[0];
    const int*   tags        = (const int*)  d_in[1];
    const float* embed       = (const float*)d_in[2];
    const float* wih_f       = (const float*)d_in[3];
    const float* whh_f       = (const float*)d_in[4];
    const float* bih_f       = (const float*)d_in[5];
    const float* bhh_f       = (const float*)d_in[6];
    const float* wih_b       = (const float*)d_in[7];
    const float* whh_b       = (const float*)d_in[8];
    const float* bih_b       = (const float*)d_in[9];
    const float* bhh_b       = (const float*)d_in[10];
    const float* w_out       = (const float*)d_in[11];
    const float* b_out       = (const float*)d_in[12];
    const float* start_trans = (const float*)d_in[13];
    const float* end_trans   = (const float*)d_in[14];
    const float* trans       = (const float*)d_in[15];
    const int*   mask        = (const int*)  d_in[16];

    char* ws = (char*)d_ws;
    f16*     xg     = (f16*)ws;     ws += (size_t)MROWS*KP*2;   // 20.97 MB
    f16*     wpack  = (f16*)ws;     ws += (size_t)NB*KP*2;      // 1.31 MB
    float*   bias2  = (float*)ws;   ws += (size_t)NB*4;         // 8 KB
    uint8_t* whhp8  = (uint8_t*)ws; ws += (size_t)1024*512;     // 0.52 MB (1024 frags x 512 B)
    f16*     xp5    = (f16*)ws;     ws += (size_t)MROWS*NB*2;   // 134.2 MB
    f16*     hcat   = (f16*)ws;     ws += (size_t)MROWS*512*2;  // 33.55 MB
    float*   emis   = (float*)ws;   ws += (size_t)MROWS*TAGS*4; // 1.18 MB

    hipLaunchKernelGGL(k_pack_wih, dim3(NB), dim3(64), 0, stream,
                       wih_f, wih_b, bih_f, bhh_f, bih_b, bhh_b, wpack, bias2);
    hipLaunchKernelGGL(k_pack_whh8, dim3(256), dim3(256), 0, stream, whh_f, whh_b, whhp8);
    hipLaunchKernelGGL(k_gather, dim3(MROWS), dim3(64), 0, stream, sentence, embed, xg);
    hipLaunchKernelGGL(k_gemm_xproj, dim3(256,16), dim3(256), 0, stream, xg, wpack, bias2, xp5);
    hipLaunchKernelGGL(k_recur, dim3(128), dim3(256), 0, stream, xp5, whhp8, hcat);
    hipLaunchKernelGGL(k_emis, dim3(MROWS/4), dim3(256), 0, stream, hcat, w_out, b_out, emis);
    hipMemsetAsync(d_out, 0, sizeof(float), stream);
    hipLaunchKernelGGL(k_crf, dim3(BATCH/4), dim3(256), 0, stream,
                       emis, tags, mask, start_trans, end_trans, trans, (float*)d_out);
}

// Round 10
// 1028.054 us; speedup vs baseline: 1.2851x; 1.2037x over previous
//
#include <hip/hip_runtime.h>
#include <hip/hip_bf16.h>
#include <hip/hip_fp8.h>
#include <stdint.h>

#define EDIM 300
#define KP   320      // padded E for MFMA K-loop
#define HDIM 256
#define G4H  1024
#define NB   2048     // both directions' gates
#define TAGS 9
#define BATCH 64
#define SEQ  512
#define MROWS (SEQ*BATCH)   // 32768

typedef _Float16 f16;
typedef _Float16 half2_t __attribute__((ext_vector_type(2)));
typedef _Float16 half8_t __attribute__((ext_vector_type(8)));
typedef float    floatx4 __attribute__((ext_vector_type(4)));
typedef uint32_t u32x2   __attribute__((ext_vector_type(2)));

__device__ __forceinline__ float fast_sigmoid(float x) {
    return __builtin_amdgcn_rcpf(1.f + __expf(-x));
}
__device__ __forceinline__ float fast_tanh(float x) {
    // 1 - 2/(e^{2x}+1); exact at +-inf via rcp(inf)=0
    return 1.f - 2.f*__builtin_amdgcn_rcpf(__expf(2.f*x) + 1.f);
}
__device__ __forceinline__ uint8_t to_e4m3(float x) {
    __hip_fp8_e4m3 q(x);
    return __builtin_bit_cast(uint8_t, q);
}

// ---- pack input-projection weights [n<1024: wih_f | n>=1024: wih_b], K padded to 320, + fused bias
__global__ void k_pack_wih(const float* __restrict__ wih_f, const float* __restrict__ wih_b,
                           const float* __restrict__ bih_f, const float* __restrict__ bhh_f,
                           const float* __restrict__ bih_b, const float* __restrict__ bhh_b,
                           f16* __restrict__ wpack, float* __restrict__ bias2) {
    int n = blockIdx.x;
    const float* src = (n < G4H) ? (wih_f + (long)n*EDIM) : (wih_b + (long)(n-G4H)*EDIM);
    for (int k = threadIdx.x; k < KP; k += 64)
        wpack[(long)n*KP + k] = (k < EDIM) ? (f16)src[k] : (f16)0.f;
    if (threadIdx.x == 0)
        bias2[n] = (n < G4H) ? (bih_f[n] + bhh_f[n]) : (bih_b[n-G4H] + bhh_b[n-G4H]);
}

// ---- pack recurrent weights into fp8-e4m3 MFMA A-fragment layout, SCALED x16
// (validated R9). frag g = fr*8 + kf of (dir,w) chunk at
// whhp8[((dir*4+w)*128 + g)*512 + lane*8].
// A[row][k] (16x16x32 fp8, 2 regs = 8 fp8/lane): row = lane&15, k = (lane>>4)*8 + j.
// gate row = (fr>>2)*256 + w*64 + (fr&3)*16 + (lane&15); k = kf*32 + (lane>>4)*8 + j.
__global__ void k_pack_whh8(const float* __restrict__ whh_f, const float* __restrict__ whh_b,
                            uint8_t* __restrict__ whhp8) {
    int idx = blockIdx.x*256 + threadIdx.x;   // 65536 = 2*4*16*8*64
    int lane = idx & 63;
    int kf = (idx >> 6) & 7;
    int fr = (idx >> 9) & 15;
    int w  = (idx >> 13) & 3;
    int dir = idx >> 15;
    const float* whh = dir ? whh_b : whh_f;
    int grow = (fr >> 2)*256 + w*64 + (fr & 3)*16 + (lane & 15);
    int k0 = kf*32 + (lane >> 4)*8;
    const float* src = whh + (long)grow*HDIM + k0;
    uint8_t tmp[8];
    #pragma unroll
    for (int j = 0; j < 8; ++j) tmp[j] = to_e4m3(src[j] * 16.f);
    *(uint2*)(whhp8 + (size_t)idx*8) = *(uint2*)tmp;
}

// ---- embedding gather, f16, row m = t*64+b, padded to KP
__global__ void k_gather(const int* __restrict__ sentence, const float* __restrict__ embed,
                         f16* __restrict__ xg) {
    int m = blockIdx.x;
    int t = m >> 6, b = m & 63;
    int tok = sentence[b*SEQ + t];
    const float* row = embed + (long)tok*EDIM;
    for (int e = threadIdx.x; e < KP; e += 64)
        xg[(long)m*KP + e] = (e < EDIM) ? (f16)row[e] : (f16)0.f;
}

// ---- xp6 GEMM, M=32768 N=2048 K=320; double-buffered global->reg prefetch.
// GATE-MAJOR epilogue (32B-contiguous stores per 16-lane group, R0-validated
// write pattern): xp6[ ((dir*64 + b)*512 + s)*1024 + (gate*256 + u) ],
// s = dir ? SEQ-1-t : t, where col = dir*1024 + gate*256 + u.
__launch_bounds__(256)
__global__ void k_gemm_xproj(const f16* __restrict__ xg, const f16* __restrict__ wpack,
                             const float* __restrict__ bias2, f16* __restrict__ xp6) {
    __shared__ __align__(16) f16 As[128*40];
    __shared__ __align__(16) f16 Bs[128*40];
    int tid = threadIdx.x;
    int bm = blockIdx.x, bn = blockIdx.y;
    int wid = tid >> 6, lane = tid & 63;
    int waveM = wid & 1, waveN = wid >> 1;
    int quad = lane >> 4, mlo = lane & 15;
    int c0 = tid,        r0 = c0 >> 2, o0 = (c0 & 3)*8;
    int c1 = tid + 256,  r1 = c1 >> 2, o1 = (c1 & 3)*8;
    const f16* ag = xg    + (long)(bm*128)*KP;
    const f16* bg = wpack + (long)(bn*128)*KP;
    uint4 pa0 = *(const uint4*)(&ag[(long)r0*KP + o0]);
    uint4 pa1 = *(const uint4*)(&ag[(long)r1*KP + o1]);
    uint4 pb0 = *(const uint4*)(&bg[(long)r0*KP + o0]);
    uint4 pb1 = *(const uint4*)(&bg[(long)r1*KP + o1]);
    floatx4 acc[4][4] = {};
    for (int k0 = 0; k0 < KP; k0 += 32) {
        *(uint4*)(&As[r0*40 + o0]) = pa0;
        *(uint4*)(&As[r1*40 + o1]) = pa1;
        *(uint4*)(&Bs[r0*40 + o0]) = pb0;
        *(uint4*)(&Bs[r1*40 + o1]) = pb1;
        __syncthreads();
        if (k0 + 32 < KP) {     // prefetch next K-tile (in flight during MFMA)
            pa0 = *(const uint4*)(&ag[(long)r0*KP + k0+32 + o0]);
            pa1 = *(const uint4*)(&ag[(long)r1*KP + k0+32 + o1]);
            pb0 = *(const uint4*)(&bg[(long)r0*KP + k0+32 + o0]);
            pb1 = *(const uint4*)(&bg[(long)r1*KP + k0+32 + o1]);
        }
        half8_t af[4], bf[4];
        #pragma unroll
        for (int i = 0; i < 4; ++i)
            af[i] = *(const half8_t*)(&As[(waveM*64 + i*16 + mlo)*40 + quad*8]);
        #pragma unroll
        for (int j = 0; j < 4; ++j)
            bf[j] = *(const half8_t*)(&Bs[(waveN*64 + j*16 + mlo)*40 + quad*8]);
        #pragma unroll
        for (int i = 0; i < 4; ++i)
            #pragma unroll
            for (int j = 0; j < 4; ++j)
                acc[i][j] = __builtin_amdgcn_mfma_f32_16x16x32_f16(af[i], bf[j], acc[i][j], 0, 0, 0);
        __syncthreads();
    }
    #pragma unroll
    for (int i = 0; i < 4; ++i)
        #pragma unroll
        for (int j = 0; j < 4; ++j) {
            int col = bn*128 + waveN*64 + j*16 + mlo;   // 0..2047
            float bv = bias2[col];
            int dir = col >> 10, grow = col & 1023;     // grow = gate*256 + u
            #pragma unroll
            for (int r = 0; r < 4; ++r) {
                int row = bm*128 + waveM*64 + i*16 + quad*4 + r;
                int t = row >> 6, bb = row & 63;
                int s = dir ? (SEQ-1-t) : t;
                xp6[((size_t)(dir*64 + bb)*512 + s)*1024 + grow] = (f16)(acc[i][j][r] + bv);
            }
        }
}

// ---- LSTM recurrence on fp8 MFMA, one WG per (dir,batch): 128 WGs, 256 threads =
// 4 waves, 1 wave/SIMD. All 128 W frags/wave in 256 AGPRs ("a" asm, zero-copy,
// validated R9). Step floor = 128 MFMA x 16 cyc = 2048 cyc/SIMD (dense-peak math);
// v10 shaves the serial tail: since every quad's 16 lanes load IDENTICAL h bytes,
// all 16 MFMA columns hold identical gates -> each lane already has all 4 gates of
// 16 units in registers. The gbuf LDS round-trip is replaced by a 60-cndmask
// in-register selection (lane (q,c) extracts unit u=(c>>2)*16+q*4+(c&3)); cell runs
// branchless on all 64 lanes; h written as one ds_write_b8/lane. x-preacts: 4
// coalesced f16 loads/lane from gate-major xp6, prefetched one step ahead. One raw
// lgkmcnt(0)+s_barrier per step.
__launch_bounds__(256, 1)
__global__ void k_recur(const f16* __restrict__ xp6, const uint8_t* __restrict__ whhp8,
                        f16* __restrict__ hcat) {
    __shared__ __align__(8) uint8_t hbuf[2][256];      // 512 B, x16-scaled e4m3 h
    int dir = blockIdx.x & 1, b = blockIdx.x >> 1;
    int tid = threadIdx.x, w = tid >> 6, lane = tid & 63;
    int q = lane >> 4;          // k-group / row-quad
    int cc4 = lane & 15;
    int sub = cc4 >> 2, rsel = cc4 & 3;
    int u = sub*16 + q*4 + rsel;        // unit owned in cell phase (bijective per wave)
    bool rlo = (rsel & 1) != 0, rhi = (rsel >> 1) != 0;
    bool slo = (sub  & 1) != 0, shi = (sub  >> 1) != 0;

    // ---- all 128 W fragments -> AGPR (2 regs each = 256 AGPRs exactly)
    const uint8_t* wbase = whhp8 + (size_t)(dir*4 + w)*65536;
    u32x2 wa[128];
    #pragma unroll
    for (int g = 0; g < 128; ++g)
        wa[g] = *(const u32x2*)(wbase + ((size_t)g*64 + lane)*8);

    if (tid < 64) ((uint32_t*)&hbuf[0][0])[tid] = 0u;

    // per-lane x source: gate-major xp6; 4 loads at gate*256 + (w*64+u), linear in s
    const f16* xs = xp6 + ((size_t)(dir*64 + b)*512)*1024 + w*64 + u;
    float xv[4];
    #pragma unroll
    for (int g = 0; g < 4; ++g) xv[g] = (float)xs[g*256];

    floatx4 zc = {0.f, 0.f, 0.f, 0.f};   // shared zero C-operand
    float cc = 0.f;
    __syncthreads();

    for (int s = 0; s < SEQ; ++s) {
        int t = dir ? (SEQ-1-s) : s;
        // prefetch next step's x (global; stays in flight across the raw barrier)
        int sp = (s+1 < SEQ) ? s+1 : s;
        float xn[4];
        #pragma unroll
        for (int g = 0; g < 4; ++g) xn[g] = (float)xs[(size_t)sp*1024 + g*256];
        // ---- 128 fp8 MFMA over K=256, A pinned in AGPR (zero-copy)
        floatx4 acc[16];
        const uint8_t* hp = &hbuf[s & 1][0];
        #pragma unroll
        for (int kf = 0; kf < 8; ++kf) {
            u32x2 bf2 = *(const u32x2*)(hp + kf*32 + q*8);
            #pragma unroll
            for (int fr = 0; fr < 16; ++fr) {
                const int g = fr*8 + kf;
                if (kf == 0)
                    asm("v_mfma_f32_16x16x32_fp8_fp8 %0, %1, %2, %3"
                        : "=&v"(acc[fr]) : "a"(wa[g]), "v"(bf2), "v"(zc));
                else
                    asm("v_mfma_f32_16x16x32_fp8_fp8 %0, %1, %2, %0"
                        : "+v"(acc[fr]) : "a"(wa[g]), "v"(bf2));
            }
        }
        // ---- in-register gate selection: all 16 cols identical, so each lane
        // extracts its unit's 4 gates with a cndmask tree (no LDS, no divergence).
        float gv[4];
        #pragma unroll
        for (int g = 0; g < 4; ++g) {
            float s0, s1, s2, s3;
            {   // select r within each sub-fragment (compile-time acc indices)
                const int f0 = g*4 + 0, f1 = g*4 + 1, f2 = g*4 + 2, f3 = g*4 + 3;
                s0 = rlo ? (rhi ? acc[f0][3] : acc[f0][1]) : (rhi ? acc[f0][2] : acc[f0][0]);
                s1 = rlo ? (rhi ? acc[f1][3] : acc[f1][1]) : (rhi ? acc[f1][2] : acc[f1][0]);
                s2 = rlo ? (rhi ? acc[f2][3] : acc[f2][1]) : (rhi ? acc[f2][2] : acc[f2][0]);
                s3 = rlo ? (rhi ? acc[f3][3] : acc[f3][1]) : (rhi ? acc[f3][2] : acc[f3][0]);
            }
            gv[g] = slo ? (shi ? s3 : s1) : (shi ? s2 : s0);
        }
        // ---- branchless cell on all 64 lanes; un-scale by 1/256
        {
            const float is = 1.f/256.f;
            float pi = __builtin_fmaf(gv[0], is, xv[0]);
            float pf = __builtin_fmaf(gv[1], is, xv[1]);
            float pg = __builtin_fmaf(gv[2], is, xv[2]);
            float po = __builtin_fmaf(gv[3], is, xv[3]);
            float si = fast_sigmoid(pi), sf = fast_sigmoid(pf);
            float tg = fast_tanh(pg),   so = fast_sigmoid(po);
            cc = __builtin_fmaf(sf, cc, si*tg);
            float hh = so * fast_tanh(cc);
            hbuf[(s+1) & 1][w*64 + u] = to_e4m3(hh * 16.f);
            hcat[((size_t)t*64 + b)*512 + dir*HDIM + w*64 + u] = (f16)hh;
        }
        #pragma unroll
        for (int g = 0; g < 4; ++g) xv[g] = xn[g];
        asm volatile("s_waitcnt lgkmcnt(0)" ::: "memory");
        __builtin_amdgcn_s_barrier();
        asm volatile("" ::: "memory");
    }
}

// ---- emissions: one wave per (t,b) row; lanes split K=512; 9 shuffle-reduced dots
__launch_bounds__(256)
__global__ void k_emis(const f16* __restrict__ hcat, const float* __restrict__ w_out,
                       const float* __restrict__ b_out, float* __restrict__ emis) {
    int r = blockIdx.x*4 + (threadIdx.x >> 6);
    int lane = threadIdx.x & 63;
    float hv[8];
    #pragma unroll
    for (int i = 0; i < 8; ++i) hv[i] = (float)hcat[(long)r*512 + lane + i*64];
    for (int tag = 0; tag < TAGS; ++tag) {
        float acc = 0.f;
        #pragma unroll
        for (int i = 0; i < 8; ++i) acc += hv[i]*w_out[tag*512 + lane + i*64];
        for (int off = 32; off; off >>= 1) acc += __shfl_xor(acc, off);
        if (lane == 0) emis[(long)r*TAGS + tag] = acc + b_out[tag];
    }
}

// ---- CRF: one wave per batch row. Gold score (lane-parallel over t) + forward logZ
__launch_bounds__(256)
__global__ void k_crf(const float* __restrict__ emis, const int* __restrict__ tags,
                      const int* __restrict__ mask, const float* __restrict__ start_trans,
                      const float* __restrict__ end_trans, const float* __restrict__ trans,
                      float* __restrict__ out) {
    int b = blockIdx.x*4 + (threadIdx.x >> 6);
    int lane = threadIdx.x & 63;
    int len = 0;
    #pragma unroll
    for (int i = 0; i < 8; ++i) len += mask[b*SEQ + lane + i*64];
    for (int off = 32; off; off >>= 1) len += __shfl_xor(len, off);
    float sc = 0.f;
    for (int i = 0; i < 8; ++i) {
        int t = 1 + lane + i*64;
        if (t < SEQ && mask[b*SEQ + t]) {
            int tp = tags[b*SEQ + t - 1], tc = tags[b*SEQ + t];
            sc += trans[tp*TAGS + tc] + emis[(long)(t*64 + b)*TAGS + tc];
        }
    }
    for (int off = 32; off; off >>= 1) sc += __shfl_xor(sc, off);
    int tag0 = tags[b*SEQ];
    sc += start_trans[tag0] + emis[(long)b*TAGS + tag0];
    sc += end_trans[tags[b*SEQ + len - 1]];
    bool act = lane < TAGS;
    int j = act ? lane : 0;
    float tcol[TAGS];
    #pragma unroll
    for (int i = 0; i < TAGS; ++i) tcol[i] = trans[i*TAGS + j];
    float alpha = act ? (start_trans[j] + emis[(long)b*TAGS + j]) : -1e30f;
    for (int t = 1; t < SEQ; ++t) {
        int mt = mask[b*SEQ + t];
        float em = emis[(long)(t*64 + b)*TAGS + j];
        float v[TAGS], mx = -1e30f;
        #pragma unroll
        for (int i = 0; i < TAGS; ++i) { v[i] = __shfl(alpha, i) + tcol[i]; mx = fmaxf(mx, v[i]); }
        float ss = 0.f;
        #pragma unroll
        for (int i = 0; i < TAGS; ++i) ss += __expf(v[i] - mx);
        float nxt = mx + __logf(ss) + em;
        if (mt && act) alpha = nxt;
    }
    float fv = act ? (alpha + end_trans[j]) : -1e30f;
    float mx = fv;
    for (int off = 32; off; off >>= 1) mx = fmaxf(mx, __shfl_xor(mx, off));
    float ss = act ? __expf(fv - mx) : 0.f;
    for (int off = 32; off; off >>= 1) ss += __shfl_xor(ss, off);
    float logZ = mx + __logf(ss);
    if (lane == 0) atomicAdd(out, (logZ - sc) * (1.0f/BATCH));
}

extern "C" void kernel_launch(void* const* d_in, const int* in_sizes, int n_in,
                              void* d_out, int out_size, void* d_ws, size_t ws_size,
                              hipStream_t stream) {
    const int*   sentence    = (const int*)  d_in[0];
    const int*   tags        = (const int*)  d_in[1];
    const float* embed       = (const float*)d_in[2];
    const float* wih_f       = (const float*)d_in[3];
    const float* whh_f       = (const float*)d_in[4];
    const float* bih_f       = (const float*)d_in[5];
    const float* bhh_f       = (const float*)d_in[6];
    const float* wih_b       = (const float*)d_in[7];
    const float* whh_b       = (const float*)d_in[8];
    const float* bih_b       = (const float*)d_in[9];
    const float* bhh_b       = (const float*)d_in[10];
    const float* w_out       = (const float*)d_in[11];
    const float* b_out       = (const float*)d_in[12];
    const float* start_trans = (const float*)d_in[13];
    const float* end_trans   = (const float*)d_in[14];
    const float* trans       = (const float*)d_in[15];
    const int*   mask        = (const int*)  d_in[16];

    char* ws = (char*)d_ws;
    f16*     xg     = (f16*)ws;     ws += (size_t)MROWS*KP*2;   // 20.97 MB
    f16*     wpack  = (f16*)ws;     ws += (size_t)NB*KP*2;      // 1.31 MB
    float*   bias2  = (float*)ws;   ws += (size_t)NB*4;         // 8 KB
    uint8_t* whhp8  = (uint8_t*)ws; ws += (size_t)1024*512;     // 0.52 MB
    f16*     xp6    = (f16*)ws;     ws += (size_t)MROWS*NB*2;   // 134.2 MB
    f16*     hcat   = (f16*)ws;     ws += (size_t)MROWS*512*2;  // 33.55 MB
    float*   emis   = (float*)ws;   ws += (size_t)MROWS*TAGS*4; // 1.18 MB

    hipLaunchKernelGGL(k_pack_wih, dim3(NB), dim3(64), 0, stream,
                       wih_f, wih_b, bih_f, bhh_f, bih_b, bhh_b, wpack, bias2);
    hipLaunchKernelGGL(k_pack_whh8, dim3(256), dim3(256), 0, stream, whh_f, whh_b, whhp8);
    hipLaunchKernelGGL(k_gather, dim3(MROWS), dim3(64), 0, stream, sentence, embed, xg);
    hipLaunchKernelGGL(k_gemm_xproj, dim3(256,16), dim3(256), 0, stream, xg, wpack, bias2, xp6);
    hipLaunchKernelGGL(k_recur, dim3(128), dim3(256), 0, stream, xp6, whhp8, hcat);
    hipLaunchKernelGGL(k_emis, dim3(MROWS/4), dim3(256), 0, stream, hcat, w_out, b_out, emis);
    hipMemsetAsync(d_out, 0, sizeof(float), stream);
    hipLaunchKernelGGL(k_crf, dim3(BATCH/4), dim3(256), 0, stream,
                       emis, tags, mask, start_trans, end_trans, trans, (float*)d_out);
}